// Round 16
// baseline (262.148 us; speedup 1.0000x reference)
//
#include <hip/hip_runtime.h>
#include <math.h>

#define G      1708
#define GP     1728         // padded per-(b,h) row stride (div by 4)
#define C4     427          // float4 chunks per row (427*4 = 1708 exactly)
#define NH     5
#define NB     16
#define NC     34
#define NND    512          // interpolation nodes per (b,h)
#define LN_EPS 1e-6f
#define LOG2E  1.4426950408889634f
#define LN2    0.6931471805599453f

// ---------------------------------------------------------------------------
// Rank-1 attention: score(i,j) = q_i * k_j  (scalars).  Hence
//   S1_i = f(q_i),  S2_i = g(q_i)   with  f(t) = sum_j exp(t k_j),
//   g(t) = sum_j v_j exp(t k_j).
// Per (b,h): tabulate {log2 f, d/dt log2 f, G=g/f, dG/dt} at NND uniform
// nodes over [qmin,qmax] (exact analytic derivatives from the same sums),
// then each row is one cubic-Hermite eval + exact diagonal correction:
//   o_i = W0 * (G(q_i) - v_i * 2^(q_i k2_i - log2 f(q_i)))      (arg <= 0)
// Replaces the O(G^2) j-loop (233M exp/layer) with O(NND*G) (70M) that is
// embarrassingly parallel.  Interp error ~ h^4/384 * kappa4 << absmax.
// ---------------------------------------------------------------------------

// prep: grid (NH,NB).  Recombine prev heads + LN (layers 2/3) -> h (regs),
// write k2 = h*WK*log2e, v = h*WV, q = h*WQ to global; reduce q/k2 min/max.
template <bool FIRST>
__global__ __launch_bounds__(256) void prep_kernel(
    const float* __restrict__ hprev, const float* __restrict__ php,
    const float* __restrict__ lna, const float* __restrict__ lnb,
    const float* __restrict__ WQ, const float* __restrict__ WK,
    const float* __restrict__ WV,
    float* __restrict__ kt, float* __restrict__ vt, float* __restrict__ qt,
    float* __restrict__ meta, float* __restrict__ hcur)
{
    __shared__ float red[16];
    const int h = blockIdx.x, b = blockIdx.y, tid = threadIdx.x;
    const size_t pbh = (size_t)b * NH + h;
    const float4* hp4 = reinterpret_cast<const float4*>(hprev + (size_t)b * G);

    // ---- phase A: combine heads (registers) + LN stats ----
    float4 acc0, acc1;
    float mean = 0.f, inv = 0.f;
    if constexpr (!FIRST) {
        const float4* p0 = reinterpret_cast<const float4*>(php + ((size_t)b * NH + 0) * GP);
        const float4* p1 = reinterpret_cast<const float4*>(php + ((size_t)b * NH + 1) * GP);
        const float4* p2 = reinterpret_cast<const float4*>(php + ((size_t)b * NH + 2) * GP);
        const float4* p3 = reinterpret_cast<const float4*>(php + ((size_t)b * NH + 3) * GP);
        const float4* p4 = reinterpret_cast<const float4*>(php + ((size_t)b * NH + 4) * GP);
        float s = 0.f, ss = 0.f;
        {   // it = 0: c = tid < 256 <= C4
            const int c = tid;
            float4 a = p0[c], t;
            t = p1[c]; a.x += t.x; a.y += t.y; a.z += t.z; a.w += t.w;
            t = p2[c]; a.x += t.x; a.y += t.y; a.z += t.z; a.w += t.w;
            t = p3[c]; a.x += t.x; a.y += t.y; a.z += t.z; a.w += t.w;
            t = p4[c]; a.x += t.x; a.y += t.y; a.z += t.z; a.w += t.w;
            acc0 = a;
            s  += (a.x + a.y) + (a.z + a.w);
            ss += (a.x * a.x + a.y * a.y) + (a.z * a.z + a.w * a.w);
        }
        {   // it = 1
            const int c = tid + 256;
            if (c < C4) {
                float4 a = p0[c], t;
                t = p1[c]; a.x += t.x; a.y += t.y; a.z += t.z; a.w += t.w;
                t = p2[c]; a.x += t.x; a.y += t.y; a.z += t.z; a.w += t.w;
                t = p3[c]; a.x += t.x; a.y += t.y; a.z += t.z; a.w += t.w;
                t = p4[c]; a.x += t.x; a.y += t.y; a.z += t.z; a.w += t.w;
                acc1 = a;
                s  += (a.x + a.y) + (a.z + a.w);
                ss += (a.x * a.x + a.y * a.y) + (a.z * a.z + a.w * a.w);
            }
        }
        for (int o = 1; o < 64; o <<= 1) {
            s  += __shfl_xor(s, o);
            ss += __shfl_xor(ss, o);
        }
        if ((tid & 63) == 0) { red[tid >> 6] = s; red[4 + (tid >> 6)] = ss; }
        __syncthreads();
        float S  = (red[0] + red[1]) + (red[2] + red[3]);
        float SS = (red[4] + red[5]) + (red[6] + red[7]);
        mean = S / (float)G;
        float var = fmaxf((SS - S * mean) / (float)(G - 1), 0.f);
        inv = 1.f / (sqrtf(var) + LN_EPS);
        __syncthreads();   // red reads done before minmax reuse
    }

    // ---- phase B: h values, k2/v/q rows to global, q & k2 min/max ----
    const float4* ga4 = reinterpret_cast<const float4*>(lna);
    const float4* gb4 = reinterpret_cast<const float4*>(lnb);
    const float4* wk4 = reinterpret_cast<const float4*>(WK + (size_t)h * G);
    const float4* wv4 = reinterpret_cast<const float4*>(WV + (size_t)h * G);
    const float4* wq4 = reinterpret_cast<const float4*>(WQ + (size_t)h * G);
    float4* kt4 = reinterpret_cast<float4*>(kt + pbh * GP);
    float4* vt4 = reinterpret_cast<float4*>(vt + pbh * GP);
    float4* qt4 = reinterpret_cast<float4*>(qt + pbh * GP);
    float4* hc4 = (!FIRST && hcur != nullptr && h == 0)
                      ? reinterpret_cast<float4*>(hcur + (size_t)b * G) : nullptr;

    float kmx = -INFINITY, kmn = INFINITY;
    float qmx = -INFINITY, qmn = INFINITY;
#pragma unroll
    for (int it = 0; it < 2; ++it) {
        const int c = tid + it * 256;
        if (it == 0 || c < C4) {
            float4 hv;
            if constexpr (FIRST) {
                hv = hp4[c];
            } else {
                float4 a = (it == 0) ? acc0 : acc1;
                float4 hp = hp4[c], ga = ga4[c], gb = gb4[c];
                hv.x = hp.x + ga.x * (a.x - mean) * inv + gb.x;
                hv.y = hp.y + ga.y * (a.y - mean) * inv + gb.y;
                hv.z = hp.z + ga.z * (a.z - mean) * inv + gb.z;
                hv.w = hp.w + ga.w * (a.w - mean) * inv + gb.w;
            }
            if (hc4) hc4[c] = hv;
            float4 wk = wk4[c], wv = wv4[c], wq = wq4[c], kl, vv, qv;
            kl.x = hv.x * wk.x * LOG2E; kl.y = hv.y * wk.y * LOG2E;
            kl.z = hv.z * wk.z * LOG2E; kl.w = hv.w * wk.w * LOG2E;
            vv.x = hv.x * wv.x; vv.y = hv.y * wv.y;
            vv.z = hv.z * wv.z; vv.w = hv.w * wv.w;
            qv.x = hv.x * wq.x; qv.y = hv.y * wq.y;
            qv.z = hv.z * wq.z; qv.w = hv.w * wq.w;
            kt4[c] = kl;
            vt4[c] = vv;
            qt4[c] = qv;
            kmx = fmaxf(kmx, fmaxf(fmaxf(kl.x, kl.y), fmaxf(kl.z, kl.w)));
            kmn = fminf(kmn, fminf(fminf(kl.x, kl.y), fminf(kl.z, kl.w)));
            qmx = fmaxf(qmx, fmaxf(fmaxf(qv.x, qv.y), fmaxf(qv.z, qv.w)));
            qmn = fminf(qmn, fminf(fminf(qv.x, qv.y), fminf(qv.z, qv.w)));
        }
    }
    for (int o = 1; o < 64; o <<= 1) {
        kmx = fmaxf(kmx, __shfl_xor(kmx, o));
        kmn = fminf(kmn, __shfl_xor(kmn, o));
        qmx = fmaxf(qmx, __shfl_xor(qmx, o));
        qmn = fminf(qmn, __shfl_xor(qmn, o));
    }
    if ((tid & 63) == 0) {
        red[tid >> 6]      = qmn; red[4 + (tid >> 6)]  = qmx;
        red[8 + (tid >> 6)] = kmn; red[12 + (tid >> 6)] = kmx;
    }
    __syncthreads();
    if (tid == 0) {
        meta[pbh * 4 + 0] = fminf(fminf(red[0], red[1]), fminf(red[2], red[3]));
        meta[pbh * 4 + 1] = fmaxf(fmaxf(red[4], red[5]), fmaxf(red[6], red[7]));
        meta[pbh * 4 + 2] = fminf(fminf(red[8], red[9]), fminf(red[10], red[11]));
        meta[pbh * 4 + 3] = fmaxf(fmaxf(red[12], red[13]), fmaxf(red[14], red[15]));
    }
}

// tables: grid (NND/4, NH, NB), 4 waves/block, one node per wave.
// At node t: F=sum e, G1=sum k2 e, Gv=sum v e, G2=sum k2 v e with
// e = 2^(t k2 - m2), m2 = max(t k2max, t k2min) (exact rank-1 offset).
// Store {log2 f, d/dt log2 f, g/f, d(g/f)/dt}.
__global__ __launch_bounds__(256) void tables_kernel(
    const float* __restrict__ kt, const float* __restrict__ vt,
    const float* __restrict__ meta, float4* __restrict__ tab)
{
    const int ng = blockIdx.x, h = blockIdx.y, b = blockIdx.z;
    const size_t pbh = (size_t)b * NH + h;
    const int w = threadIdx.x >> 6, lane = threadIdx.x & 63;
    const int n = ng * 4 + w;

    const float qmn = meta[pbh * 4 + 0], qmx = meta[pbh * 4 + 1];
    const float kmn = meta[pbh * 4 + 2], kmx = meta[pbh * 4 + 3];
    const float rng = fmaxf(qmx - qmn, 1e-6f);
    const float t   = qmn + rng * ((float)n / (float)(NND - 1));
    const float m2  = fmaxf(t * kmx, t * kmn);

    const float* kp = kt + pbh * GP;
    const float* vp = vt + pbh * GP;
    float F = 0.f, G1 = 0.f, Gv = 0.f, G2 = 0.f;
    for (int j = lane; j < G; j += 64) {
        const float k2 = kp[j], vv = vp[j];
        const float e  = __builtin_amdgcn_exp2f(fmaf(t, k2, -m2));
        const float ve = vv * e;
        F  += e;
        G1  = fmaf(k2, e, G1);
        Gv += ve;
        G2  = fmaf(k2, ve, G2);
    }
    for (int o = 1; o < 64; o <<= 1) {
        F  += __shfl_xor(F, o);
        G1 += __shfl_xor(G1, o);
        Gv += __shfl_xor(Gv, o);
        G2 += __shfl_xor(G2, o);
    }
    if (lane == 0) {
        float4 T;
        T.x = m2 + __builtin_amdgcn_logf(F);        // log2 f
        T.y = G1 / F;                               // d/dt log2 f (k2 absorbs ln2)
        T.z = Gv / F;                               // G = g/f
        T.w = LN2 * (G2 * F - Gv * G1) / (F * F);   // dG/dt
        tab[pbh * NND + n] = T;
    }
}

// rows: grid (7, NH, NB).  One row per thread: cubic Hermite eval of
// log2 f and G at t = q_i, then exact diagonal correction.
__global__ __launch_bounds__(256) void rows_kernel(
    const float* __restrict__ kt, const float* __restrict__ vt,
    const float* __restrict__ qt, const float* __restrict__ meta,
    const float4* __restrict__ tab, const float* __restrict__ W0,
    float* __restrict__ ph)
{
    const int h = blockIdx.y, b = blockIdx.z;
    const int i = blockIdx.x * 256 + threadIdx.x;
    if (i >= G) return;
    const size_t pbh = (size_t)b * NH + h;

    const float qmn = meta[pbh * 4 + 0], qmx = meta[pbh * 4 + 1];
    const float rng = fmaxf(qmx - qmn, 1e-6f);
    const float hstep = rng / (float)(NND - 1);
    const float t = qt[pbh * GP + i];

    float u = (t - qmn) / hstep;
    int n = (int)floorf(u);
    n = n < 0 ? 0 : (n > NND - 2 ? NND - 2 : n);
    float s = u - (float)n;
    s = s < 0.f ? 0.f : (s > 1.f ? 1.f : s);

    const float4 T0 = tab[pbh * NND + n];
    const float4 T1 = tab[pbh * NND + n + 1];
    const float s2 = s * s, s3 = s2 * s;
    const float h00 = 2.f * s3 - 3.f * s2 + 1.f;
    const float h10 = s3 - 2.f * s2 + s;
    const float h01 = 3.f * s2 - 2.f * s3;
    const float h11 = s3 - s2;

    const float log2f = T0.x * h00 + T1.x * h01 + hstep * (T0.y * h10 + T1.y * h11);
    const float Gval  = T0.z * h00 + T1.z * h01 + hstep * (T0.w * h10 + T1.w * h11);

    const float k2i = kt[pbh * GP + i];
    const float vi  = vt[pbh * GP + i];
    const float eof = __builtin_amdgcn_exp2f(fmaf(t, k2i, -log2f));  // arg <= 0
    ph[pbh * GP + i] = W0[h] * (Gval - vi * eof);
}

// ---------------------------------------------------------------------------
// One logit per block: recombine layer-3 heads + LN on the fly, dot with
// fc row c.  grid (NC, NB) = 544 blocks.  (r0/r6/r15-proven, unchanged)
// ---------------------------------------------------------------------------
__global__ __launch_bounds__(256) void logits_kernel(
    const float* __restrict__ hprev, const float* __restrict__ php,
    const float* __restrict__ lna, const float* __restrict__ lnb,
    const float* __restrict__ fcw, const float* __restrict__ fcb,
    float* __restrict__ lgt)
{
    __shared__ __align__(16) float arow[G];
    __shared__ float red[8];
    const int c = blockIdx.x, b = blockIdx.y, tid = threadIdx.x;

    const float4* p0 = reinterpret_cast<const float4*>(php + ((size_t)b * NH + 0) * GP);
    const float4* p1 = reinterpret_cast<const float4*>(php + ((size_t)b * NH + 1) * GP);
    const float4* p2 = reinterpret_cast<const float4*>(php + ((size_t)b * NH + 2) * GP);
    const float4* p3 = reinterpret_cast<const float4*>(php + ((size_t)b * NH + 3) * GP);
    const float4* p4 = reinterpret_cast<const float4*>(php + ((size_t)b * NH + 4) * GP);
    float4* ar4 = reinterpret_cast<float4*>(arow);

    float s = 0.f, ss = 0.f;
    for (int k = tid; k < C4; k += 256) {
        float4 a = p0[k], t;
        t = p1[k]; a.x += t.x; a.y += t.y; a.z += t.z; a.w += t.w;
        t = p2[k]; a.x += t.x; a.y += t.y; a.z += t.z; a.w += t.w;
        t = p3[k]; a.x += t.x; a.y += t.y; a.z += t.z; a.w += t.w;
        t = p4[k]; a.x += t.x; a.y += t.y; a.z += t.z; a.w += t.w;
        ar4[k] = a;
        s  += (a.x + a.y) + (a.z + a.w);
        ss += (a.x * a.x + a.y * a.y) + (a.z * a.z + a.w * a.w);
    }
    for (int o = 1; o < 64; o <<= 1) {
        s  += __shfl_xor(s, o);
        ss += __shfl_xor(ss, o);
    }
    if ((tid & 63) == 0) { red[tid >> 6] = s; red[4 + (tid >> 6)] = ss; }
    __syncthreads();
    float S  = (red[0] + red[1]) + (red[2] + red[3]);
    float SS = (red[4] + red[5]) + (red[6] + red[7]);
    const float mean = S / (float)G;
    const float var  = fmaxf((SS - S * mean) / (float)(G - 1), 0.f);
    const float inv  = 1.f / (sqrtf(var) + LN_EPS);

    const float4* hp4 = reinterpret_cast<const float4*>(hprev + (size_t)b * G);
    const float4* ga4 = reinterpret_cast<const float4*>(lna);
    const float4* gb4 = reinterpret_cast<const float4*>(lnb);
    const float4* w4  = reinterpret_cast<const float4*>(fcw + (size_t)c * G);
    float acc = 0.f;
    for (int k = tid; k < C4; k += 256) {
        float4 a = ar4[k], hp = hp4[k], ga = ga4[k], gb = gb4[k], w = w4[k];
        float hx = hp.x + ga.x * (a.x - mean) * inv + gb.x;
        float hy = hp.y + ga.y * (a.y - mean) * inv + gb.y;
        float hz = hp.z + ga.z * (a.z - mean) * inv + gb.z;
        float hw = hp.w + ga.w * (a.w - mean) * inv + gb.w;
        acc += (hx * w.x + hy * w.y) + (hz * w.z + hw * w.w);
    }
    for (int o = 1; o < 64; o <<= 1) acc += __shfl_xor(acc, o);
    __syncthreads();
    if ((tid & 63) == 0) red[tid >> 6] = acc;
    __syncthreads();
    if (tid == 0)
        lgt[(size_t)b * NC + c] =
            (red[0] + red[1]) + (red[2] + red[3]) + fcb[c];
}

// out = log_softmax(logits) — one wave per batch row  (proven)
__global__ __launch_bounds__(64) void lsm_kernel(
    const float* __restrict__ lgt, float* __restrict__ out)
{
    const int b = blockIdx.x, tid = threadIdx.x;
    float l = (tid < NC) ? lgt[(size_t)b * NC + tid] : -INFINITY;
    float mm = l;
    for (int o = 32; o; o >>= 1) mm = fmaxf(mm, __shfl_xor(mm, o));
    float e = (tid < NC) ? expf(l - mm) : 0.f;
    float se = e;
    for (int o = 32; o; o >>= 1) se += __shfl_xor(se, o);
    if (tid < NC) out[(size_t)b * NC + tid] = l - mm - logf(se);
}

// ---------------------------------------------------------------------------
extern "C" void kernel_launch(void* const* d_in, const int* in_sizes, int n_in,
                              void* d_out, int out_size, void* d_ws, size_t ws_size,
                              hipStream_t stream)
{
    const float* x    = (const float*)d_in[0];
    const float* WQ1  = (const float*)d_in[1];
    const float* WK1  = (const float*)d_in[2];
    const float* WV1  = (const float*)d_in[3];
    const float* W01  = (const float*)d_in[4];
    const float* WQ2  = (const float*)d_in[5];
    const float* WK2  = (const float*)d_in[6];
    const float* WV2  = (const float*)d_in[7];
    const float* W02  = (const float*)d_in[8];
    const float* WQ3  = (const float*)d_in[9];
    const float* WK3  = (const float*)d_in[10];
    const float* WV3  = (const float*)d_in[11];
    const float* W03  = (const float*)d_in[12];
    const float* lna  = (const float*)d_in[13];
    const float* lnb  = (const float*)d_in[14];
    const float* fcw  = (const float*)d_in[15];
    const float* fcb  = (const float*)d_in[16];
    float* out = (float*)d_out;

    const size_t PHS = (size_t)NB * NH * GP;     // 138240 floats (div 4)
    float* kt   = (float*)d_ws;                  // [NB*NH, GP] k*log2e
    float* vt   = kt + PHS;                      // [NB*NH, GP] v
    float* qt   = vt + PHS;                      // [NB*NH, GP] q
    float* pha  = qt + PHS;                      // per-head rows (L1/L3)
    float* phb  = pha + PHS;                     // per-head rows (L2)
    float* h1   = phb + PHS;                     // [NB,G]
    float* h2   = h1 + (size_t)NB * G;           // [NB,G]
    float* tabf = h2 + (size_t)NB * G;           // [NB*NH, NND] float4
    float4* tab = reinterpret_cast<float4*>(tabf);
    float* meta = tabf + (size_t)NB * NH * NND * 4;  // [NB*NH, 4]
    float* lgt  = meta + (size_t)NB * NH * 4;    // [NB,NC]

    const dim3 pgrid(NH, NB);                    // 80 blocks
    const dim3 tgrid(NND / 4, NH, NB);           // 10240 blocks
    const dim3 rgrid(7, NH, NB);                 // 560 blocks (7*256 >= G)

    // layer 1
    prep_kernel<true><<<pgrid, 256, 0, stream>>>(
        x, nullptr, lna, lnb, WQ1, WK1, WV1, kt, vt, qt, meta, nullptr);
    tables_kernel<<<tgrid, 256, 0, stream>>>(kt, vt, meta, tab);
    rows_kernel<<<rgrid, 256, 0, stream>>>(kt, vt, qt, meta, tab, W01, pha);
    // layer 2: h1 = x + LN(combine(pha))
    prep_kernel<false><<<pgrid, 256, 0, stream>>>(
        x, pha, lna, lnb, WQ2, WK2, WV2, kt, vt, qt, meta, h1);
    tables_kernel<<<tgrid, 256, 0, stream>>>(kt, vt, meta, tab);
    rows_kernel<<<rgrid, 256, 0, stream>>>(kt, vt, qt, meta, tab, W02, phb);
    // layer 3: h2 = h1 + LN(combine(phb))
    prep_kernel<false><<<pgrid, 256, 0, stream>>>(
        h1, phb, lna, lnb, WQ3, WK3, WV3, kt, vt, qt, meta, h2);
    tables_kernel<<<tgrid, 256, 0, stream>>>(kt, vt, meta, tab);
    rows_kernel<<<rgrid, 256, 0, stream>>>(kt, vt, qt, meta, tab, W03, pha);
    // tail
    logits_kernel<<<dim3(NC, NB), 256, 0, stream>>>(
        h2, pha, lna, lnb, fcw, fcb, lgt);
    lsm_kernel<<<NB, 64, 0, stream>>>(lgt, out);
}

// Round 18
// 183.562 us; speedup vs baseline: 1.4281x; 1.4281x over previous
//
#include <hip/hip_runtime.h>
#include <math.h>

#define G      1708
#define GP     1728         // padded per-(b,h) row stride (div by 4)
#define C4     427          // float4 chunks per row (427*4 = 1708 exactly)
#define NH     5
#define NB     16
#define NC     34
#define NND    512          // interpolation nodes per (b,h)
#define NPB    16           // nodes per block (4 waves x 4 nodes)
#define LN_EPS 1e-6f
#define LOG2E  1.4426950408889634f
#define LN2    0.6931471805599453f

// ---------------------------------------------------------------------------
// Rank-1 attention via function tabulation (r16-proven correct, absmax
// unchanged): S1_i = f(q_i), S2_i = g(q_i) with f(t)=sum_j exp(t k_j),
// g(t)=sum_j v_j exp(t k_j).  Tabulate {log2 f, dlog2f, g/f, d(g/f)} at NND
// uniform nodes; rows do cubic Hermite + exact diagonal correction.
// r17 change: tables_kernel restructured to the proven attn phase-C issue
// shape — k/v staged in LDS once per block, 16 nodes amortized per block,
// float4 LDS reads feeding 16 exps/chunk/wave (r16's scalar-VMEM version
// was 4x issue-inefficient: 2 dependent loads per exp, 52.6us measured).
// ---------------------------------------------------------------------------

// prep: grid (NH,NB).  Recombine prev heads + LN (layers 2/3) -> h (regs),
// write k2 = h*WK*log2e, v = h*WV, q = h*WQ to global; reduce q/k2 min/max.
template <bool FIRST>
__global__ __launch_bounds__(256) void prep_kernel(
    const float* __restrict__ hprev, const float* __restrict__ php,
    const float* __restrict__ lna, const float* __restrict__ lnb,
    const float* __restrict__ WQ, const float* __restrict__ WK,
    const float* __restrict__ WV,
    float* __restrict__ kt, float* __restrict__ vt, float* __restrict__ qt,
    float* __restrict__ meta, float* __restrict__ hcur)
{
    __shared__ float red[16];
    const int h = blockIdx.x, b = blockIdx.y, tid = threadIdx.x;
    const size_t pbh = (size_t)b * NH + h;
    const float4* hp4 = reinterpret_cast<const float4*>(hprev + (size_t)b * G);

    // ---- phase A: combine heads (registers) + LN stats ----
    float4 acc0, acc1;
    float mean = 0.f, inv = 0.f;
    if constexpr (!FIRST) {
        const float4* p0 = reinterpret_cast<const float4*>(php + ((size_t)b * NH + 0) * GP);
        const float4* p1 = reinterpret_cast<const float4*>(php + ((size_t)b * NH + 1) * GP);
        const float4* p2 = reinterpret_cast<const float4*>(php + ((size_t)b * NH + 2) * GP);
        const float4* p3 = reinterpret_cast<const float4*>(php + ((size_t)b * NH + 3) * GP);
        const float4* p4 = reinterpret_cast<const float4*>(php + ((size_t)b * NH + 4) * GP);
        float s = 0.f, ss = 0.f;
        {   // it = 0: c = tid < 256 <= C4
            const int c = tid;
            float4 a = p0[c], t;
            t = p1[c]; a.x += t.x; a.y += t.y; a.z += t.z; a.w += t.w;
            t = p2[c]; a.x += t.x; a.y += t.y; a.z += t.z; a.w += t.w;
            t = p3[c]; a.x += t.x; a.y += t.y; a.z += t.z; a.w += t.w;
            t = p4[c]; a.x += t.x; a.y += t.y; a.z += t.z; a.w += t.w;
            acc0 = a;
            s  += (a.x + a.y) + (a.z + a.w);
            ss += (a.x * a.x + a.y * a.y) + (a.z * a.z + a.w * a.w);
        }
        {   // it = 1
            const int c = tid + 256;
            if (c < C4) {
                float4 a = p0[c], t;
                t = p1[c]; a.x += t.x; a.y += t.y; a.z += t.z; a.w += t.w;
                t = p2[c]; a.x += t.x; a.y += t.y; a.z += t.z; a.w += t.w;
                t = p3[c]; a.x += t.x; a.y += t.y; a.z += t.z; a.w += t.w;
                t = p4[c]; a.x += t.x; a.y += t.y; a.z += t.z; a.w += t.w;
                acc1 = a;
                s  += (a.x + a.y) + (a.z + a.w);
                ss += (a.x * a.x + a.y * a.y) + (a.z * a.z + a.w * a.w);
            }
        }
        for (int o = 1; o < 64; o <<= 1) {
            s  += __shfl_xor(s, o);
            ss += __shfl_xor(ss, o);
        }
        if ((tid & 63) == 0) { red[tid >> 6] = s; red[4 + (tid >> 6)] = ss; }
        __syncthreads();
        float S  = (red[0] + red[1]) + (red[2] + red[3]);
        float SS = (red[4] + red[5]) + (red[6] + red[7]);
        mean = S / (float)G;
        float var = fmaxf((SS - S * mean) / (float)(G - 1), 0.f);
        inv = 1.f / (sqrtf(var) + LN_EPS);
        __syncthreads();   // red reads done before minmax reuse
    }

    // ---- phase B: h values, k2/v/q rows to global, q & k2 min/max ----
    const float4* ga4 = reinterpret_cast<const float4*>(lna);
    const float4* gb4 = reinterpret_cast<const float4*>(lnb);
    const float4* wk4 = reinterpret_cast<const float4*>(WK + (size_t)h * G);
    const float4* wv4 = reinterpret_cast<const float4*>(WV + (size_t)h * G);
    const float4* wq4 = reinterpret_cast<const float4*>(WQ + (size_t)h * G);
    float4* kt4 = reinterpret_cast<float4*>(kt + pbh * GP);
    float4* vt4 = reinterpret_cast<float4*>(vt + pbh * GP);
    float4* qt4 = reinterpret_cast<float4*>(qt + pbh * GP);
    float4* hc4 = (!FIRST && hcur != nullptr && h == 0)
                      ? reinterpret_cast<float4*>(hcur + (size_t)b * G) : nullptr;

    float kmx = -INFINITY, kmn = INFINITY;
    float qmx = -INFINITY, qmn = INFINITY;
#pragma unroll
    for (int it = 0; it < 2; ++it) {
        const int c = tid + it * 256;
        if (it == 0 || c < C4) {
            float4 hv;
            if constexpr (FIRST) {
                hv = hp4[c];
            } else {
                float4 a = (it == 0) ? acc0 : acc1;
                float4 hp = hp4[c], ga = ga4[c], gb = gb4[c];
                hv.x = hp.x + ga.x * (a.x - mean) * inv + gb.x;
                hv.y = hp.y + ga.y * (a.y - mean) * inv + gb.y;
                hv.z = hp.z + ga.z * (a.z - mean) * inv + gb.z;
                hv.w = hp.w + ga.w * (a.w - mean) * inv + gb.w;
            }
            if (hc4) hc4[c] = hv;
            float4 wk = wk4[c], wv = wv4[c], wq = wq4[c], kl, vv, qv;
            kl.x = hv.x * wk.x * LOG2E; kl.y = hv.y * wk.y * LOG2E;
            kl.z = hv.z * wk.z * LOG2E; kl.w = hv.w * wk.w * LOG2E;
            vv.x = hv.x * wv.x; vv.y = hv.y * wv.y;
            vv.z = hv.z * wv.z; vv.w = hv.w * wv.w;
            qv.x = hv.x * wq.x; qv.y = hv.y * wq.y;
            qv.z = hv.z * wq.z; qv.w = hv.w * wq.w;
            kt4[c] = kl;
            vt4[c] = vv;
            qt4[c] = qv;
            kmx = fmaxf(kmx, fmaxf(fmaxf(kl.x, kl.y), fmaxf(kl.z, kl.w)));
            kmn = fminf(kmn, fminf(fminf(kl.x, kl.y), fminf(kl.z, kl.w)));
            qmx = fmaxf(qmx, fmaxf(fmaxf(qv.x, qv.y), fmaxf(qv.z, qv.w)));
            qmn = fminf(qmn, fminf(fminf(qv.x, qv.y), fminf(qv.z, qv.w)));
        }
    }
    for (int o = 1; o < 64; o <<= 1) {
        kmx = fmaxf(kmx, __shfl_xor(kmx, o));
        kmn = fminf(kmn, __shfl_xor(kmn, o));
        qmx = fmaxf(qmx, __shfl_xor(qmx, o));
        qmn = fminf(qmn, __shfl_xor(qmn, o));
    }
    if ((tid & 63) == 0) {
        red[tid >> 6]      = qmn; red[4 + (tid >> 6)]  = qmx;
        red[8 + (tid >> 6)] = kmn; red[12 + (tid >> 6)] = kmx;
    }
    __syncthreads();
    if (tid == 0) {
        meta[pbh * 4 + 0] = fminf(fminf(red[0], red[1]), fminf(red[2], red[3]));
        meta[pbh * 4 + 1] = fmaxf(fmaxf(red[4], red[5]), fmaxf(red[6], red[7]));
        meta[pbh * 4 + 2] = fminf(fminf(red[8], red[9]), fminf(red[10], red[11]));
        meta[pbh * 4 + 3] = fmaxf(fmaxf(red[12], red[13]), fmaxf(red[14], red[15]));
    }
}

// tables: grid (NND/NPB, NH, NB) = (32,5,16) = 2560 blocks.  k/v staged in
// LDS once per block; each of 4 waves owns 4 nodes in registers; j-loop
// reads float4 pairs from LDS feeding 16 exps per chunk per wave.
__global__ __launch_bounds__(256, 8) void tables_kernel(
    const float* __restrict__ kt, const float* __restrict__ vt,
    const float* __restrict__ meta, float4* __restrict__ tab)
{
    __shared__ __align__(16) float krow[G];
    __shared__ __align__(16) float vrow[G];

    const int ng = blockIdx.x, h = blockIdx.y, b = blockIdx.z;
    const size_t pbh = (size_t)b * NH + h;
    const int tid = threadIdx.x;
    const int w = tid >> 6, lane = tid & 63;

    // stage k/v rows into LDS
    const float4* ktg = reinterpret_cast<const float4*>(kt + pbh * GP);
    const float4* vtg = reinterpret_cast<const float4*>(vt + pbh * GP);
    float4* kr4 = reinterpret_cast<float4*>(krow);
    float4* vr4 = reinterpret_cast<float4*>(vrow);
    for (int c = tid; c < C4; c += 256) { kr4[c] = ktg[c]; vr4[c] = vtg[c]; }

    const float qmn = meta[pbh * 4 + 0], qmx = meta[pbh * 4 + 1];
    const float kmn = meta[pbh * 4 + 2], kmx = meta[pbh * 4 + 3];
    const float rng = fmaxf(qmx - qmn, 1e-6f);
    const int nb = ng * NPB + w * 4;

    float t[4], m2[4], F[4], G1[4], Gv[4], G2[4];
#pragma unroll
    for (int r = 0; r < 4; ++r) {
        t[r]  = qmn + rng * ((float)(nb + r) / (float)(NND - 1));
        m2[r] = fmaxf(t[r] * kmx, t[r] * kmn);
        F[r] = 0.f; G1[r] = 0.f; Gv[r] = 0.f; G2[r] = 0.f;
    }
    __syncthreads();

    for (int c = lane; c < C4; c += 64) {
        const float4 kk = kr4[c];
        const float4 vv = vr4[c];
#pragma unroll
        for (int r = 0; r < 4; ++r) {
            const float tt = t[r], mm = m2[r];
            const float e0 = __builtin_amdgcn_exp2f(fmaf(tt, kk.x, -mm));
            const float e1 = __builtin_amdgcn_exp2f(fmaf(tt, kk.y, -mm));
            const float e2 = __builtin_amdgcn_exp2f(fmaf(tt, kk.z, -mm));
            const float e3 = __builtin_amdgcn_exp2f(fmaf(tt, kk.w, -mm));
            F[r] += (e0 + e1) + (e2 + e3);
            G1[r] = fmaf(kk.x, e0, G1[r]);
            G1[r] = fmaf(kk.y, e1, G1[r]);
            G1[r] = fmaf(kk.z, e2, G1[r]);
            G1[r] = fmaf(kk.w, e3, G1[r]);
            const float ve0 = vv.x * e0, ve1 = vv.y * e1;
            const float ve2 = vv.z * e2, ve3 = vv.w * e3;
            Gv[r] += (ve0 + ve1) + (ve2 + ve3);
            G2[r] = fmaf(kk.x, ve0, G2[r]);
            G2[r] = fmaf(kk.y, ve1, G2[r]);
            G2[r] = fmaf(kk.z, ve2, G2[r]);
            G2[r] = fmaf(kk.w, ve3, G2[r]);
        }
    }

#pragma unroll
    for (int r = 0; r < 4; ++r) {
        for (int o = 1; o < 64; o <<= 1) {
            F[r]  += __shfl_xor(F[r], o);
            G1[r] += __shfl_xor(G1[r], o);
            Gv[r] += __shfl_xor(Gv[r], o);
            G2[r] += __shfl_xor(G2[r], o);
        }
    }
    if (lane == 0) {
#pragma unroll
        for (int r = 0; r < 4; ++r) {
            float4 T;
            T.x = m2[r] + __builtin_amdgcn_logf(F[r]);          // log2 f
            T.y = G1[r] / F[r];                                 // dlog2f/dt
            T.z = Gv[r] / F[r];                                 // G = g/f
            T.w = LN2 * (G2[r] * F[r] - Gv[r] * G1[r]) / (F[r] * F[r]); // dG/dt
            tab[pbh * NND + nb + r] = T;
        }
    }
}

// rows: grid (7, NH, NB).  One row per thread: cubic Hermite eval of
// log2 f and G at t = q_i, then exact diagonal correction.
__global__ __launch_bounds__(256) void rows_kernel(
    const float* __restrict__ kt, const float* __restrict__ vt,
    const float* __restrict__ qt, const float* __restrict__ meta,
    const float4* __restrict__ tab, const float* __restrict__ W0,
    float* __restrict__ ph)
{
    const int h = blockIdx.y, b = blockIdx.z;
    const int i = blockIdx.x * 256 + threadIdx.x;
    if (i >= G) return;
    const size_t pbh = (size_t)b * NH + h;

    const float qmn = meta[pbh * 4 + 0], qmx = meta[pbh * 4 + 1];
    const float rng = fmaxf(qmx - qmn, 1e-6f);
    const float hstep = rng / (float)(NND - 1);
    const float t = qt[pbh * GP + i];

    float u = (t - qmn) / hstep;
    int n = (int)floorf(u);
    n = n < 0 ? 0 : (n > NND - 2 ? NND - 2 : n);
    float s = u - (float)n;
    s = s < 0.f ? 0.f : (s > 1.f ? 1.f : s);

    const float4 T0 = tab[pbh * NND + n];
    const float4 T1 = tab[pbh * NND + n + 1];
    const float s2 = s * s, s3 = s2 * s;
    const float h00 = 2.f * s3 - 3.f * s2 + 1.f;
    const float h10 = s3 - 2.f * s2 + s;
    const float h01 = 3.f * s2 - 2.f * s3;
    const float h11 = s3 - s2;

    const float log2f = T0.x * h00 + T1.x * h01 + hstep * (T0.y * h10 + T1.y * h11);
    const float Gval  = T0.z * h00 + T1.z * h01 + hstep * (T0.w * h10 + T1.w * h11);

    const float k2i = kt[pbh * GP + i];
    const float vi  = vt[pbh * GP + i];
    const float eof = __builtin_amdgcn_exp2f(fmaf(t, k2i, -log2f));  // arg <= 0
    ph[pbh * GP + i] = W0[h] * (Gval - vi * eof);
}

// ---------------------------------------------------------------------------
// One logit per block: recombine layer-3 heads + LN on the fly, dot with
// fc row c.  grid (NC, NB) = 544 blocks.  (proven, unchanged)
// ---------------------------------------------------------------------------
__global__ __launch_bounds__(256) void logits_kernel(
    const float* __restrict__ hprev, const float* __restrict__ php,
    const float* __restrict__ lna, const float* __restrict__ lnb,
    const float* __restrict__ fcw, const float* __restrict__ fcb,
    float* __restrict__ lgt)
{
    __shared__ __align__(16) float arow[G];
    __shared__ float red[8];
    const int c = blockIdx.x, b = blockIdx.y, tid = threadIdx.x;

    const float4* p0 = reinterpret_cast<const float4*>(php + ((size_t)b * NH + 0) * GP);
    const float4* p1 = reinterpret_cast<const float4*>(php + ((size_t)b * NH + 1) * GP);
    const float4* p2 = reinterpret_cast<const float4*>(php + ((size_t)b * NH + 2) * GP);
    const float4* p3 = reinterpret_cast<const float4*>(php + ((size_t)b * NH + 3) * GP);
    const float4* p4 = reinterpret_cast<const float4*>(php + ((size_t)b * NH + 4) * GP);
    float4* ar4 = reinterpret_cast<float4*>(arow);

    float s = 0.f, ss = 0.f;
    for (int k = tid; k < C4; k += 256) {
        float4 a = p0[k], t;
        t = p1[k]; a.x += t.x; a.y += t.y; a.z += t.z; a.w += t.w;
        t = p2[k]; a.x += t.x; a.y += t.y; a.z += t.z; a.w += t.w;
        t = p3[k]; a.x += t.x; a.y += t.y; a.z += t.z; a.w += t.w;
        t = p4[k]; a.x += t.x; a.y += t.y; a.z += t.z; a.w += t.w;
        ar4[k] = a;
        s  += (a.x + a.y) + (a.z + a.w);
        ss += (a.x * a.x + a.y * a.y) + (a.z * a.z + a.w * a.w);
    }
    for (int o = 1; o < 64; o <<= 1) {
        s  += __shfl_xor(s, o);
        ss += __shfl_xor(ss, o);
    }
    if ((tid & 63) == 0) { red[tid >> 6] = s; red[4 + (tid >> 6)] = ss; }
    __syncthreads();
    float S  = (red[0] + red[1]) + (red[2] + red[3]);
    float SS = (red[4] + red[5]) + (red[6] + red[7]);
    const float mean = S / (float)G;
    const float var  = fmaxf((SS - S * mean) / (float)(G - 1), 0.f);
    const float inv  = 1.f / (sqrtf(var) + LN_EPS);

    const float4* hp4 = reinterpret_cast<const float4*>(hprev + (size_t)b * G);
    const float4* ga4 = reinterpret_cast<const float4*>(lna);
    const float4* gb4 = reinterpret_cast<const float4*>(lnb);
    const float4* w4  = reinterpret_cast<const float4*>(fcw + (size_t)c * G);
    float acc = 0.f;
    for (int k = tid; k < C4; k += 256) {
        float4 a = ar4[k], hp = hp4[k], ga = ga4[k], gb = gb4[k], w = w4[k];
        float hx = hp.x + ga.x * (a.x - mean) * inv + gb.x;
        float hy = hp.y + ga.y * (a.y - mean) * inv + gb.y;
        float hz = hp.z + ga.z * (a.z - mean) * inv + gb.z;
        float hw = hp.w + ga.w * (a.w - mean) * inv + gb.w;
        acc += (hx * w.x + hy * w.y) + (hz * w.z + hw * w.w);
    }
    for (int o = 1; o < 64; o <<= 1) acc += __shfl_xor(acc, o);
    __syncthreads();
    if ((tid & 63) == 0) red[tid >> 6] = acc;
    __syncthreads();
    if (tid == 0)
        lgt[(size_t)b * NC + c] =
            (red[0] + red[1]) + (red[2] + red[3]) + fcb[c];
}

// out = log_softmax(logits) — one wave per batch row  (proven)
__global__ __launch_bounds__(64) void lsm_kernel(
    const float* __restrict__ lgt, float* __restrict__ out)
{
    const int b = blockIdx.x, tid = threadIdx.x;
    float l = (tid < NC) ? lgt[(size_t)b * NC + tid] : -INFINITY;
    float mm = l;
    for (int o = 32; o; o >>= 1) mm = fmaxf(mm, __shfl_xor(mm, o));
    float e = (tid < NC) ? expf(l - mm) : 0.f;
    float se = e;
    for (int o = 32; o; o >>= 1) se += __shfl_xor(se, o);
    if (tid < NC) out[(size_t)b * NC + tid] = l - mm - logf(se);
}

// ---------------------------------------------------------------------------
extern "C" void kernel_launch(void* const* d_in, const int* in_sizes, int n_in,
                              void* d_out, int out_size, void* d_ws, size_t ws_size,
                              hipStream_t stream)
{
    const float* x    = (const float*)d_in[0];
    const float* WQ1  = (const float*)d_in[1];
    const float* WK1  = (const float*)d_in[2];
    const float* WV1  = (const float*)d_in[3];
    const float* W01  = (const float*)d_in[4];
    const float* WQ2  = (const float*)d_in[5];
    const float* WK2  = (const float*)d_in[6];
    const float* WV2  = (const float*)d_in[7];
    const float* W02  = (const float*)d_in[8];
    const float* WQ3  = (const float*)d_in[9];
    const float* WK3  = (const float*)d_in[10];
    const float* WV3  = (const float*)d_in[11];
    const float* W03  = (const float*)d_in[12];
    const float* lna  = (const float*)d_in[13];
    const float* lnb  = (const float*)d_in[14];
    const float* fcw  = (const float*)d_in[15];
    const float* fcb  = (const float*)d_in[16];
    float* out = (float*)d_out;

    const size_t PHS = (size_t)NB * NH * GP;     // 138240 floats (div 4)
    float* kt   = (float*)d_ws;                  // [NB*NH, GP] k*log2e
    float* vt   = kt + PHS;                      // [NB*NH, GP] v
    float* qt   = vt + PHS;                      // [NB*NH, GP] q
    float* pha  = qt + PHS;                      // per-head rows (L1/L3)
    float* phb  = pha + PHS;                     // per-head rows (L2)
    float* h1   = phb + PHS;                     // [NB,G]
    float* h2   = h1 + (size_t)NB * G;           // [NB,G]
    float* tabf = h2 + (size_t)NB * G;           // [NB*NH, NND] float4
    float4* tab = reinterpret_cast<float4*>(tabf);
    float* meta = tabf + (size_t)NB * NH * NND * 4;  // [NB*NH, 4]
    float* lgt  = meta + (size_t)NB * NH * 4;    // [NB,NC]

    const dim3 pgrid(NH, NB);                    // 80 blocks
    const dim3 tgrid(NND / NPB, NH, NB);         // (32,5,16) = 2560 blocks
    const dim3 rgrid(7, NH, NB);                 // 560 blocks (7*256 >= G)

    // layer 1
    prep_kernel<true><<<pgrid, 256, 0, stream>>>(
        x, nullptr, lna, lnb, WQ1, WK1, WV1, kt, vt, qt, meta, nullptr);
    tables_kernel<<<tgrid, 256, 0, stream>>>(kt, vt, meta, tab);
    rows_kernel<<<rgrid, 256, 0, stream>>>(kt, vt, qt, meta, tab, W01, pha);
    // layer 2: h1 = x + LN(combine(pha))
    prep_kernel<false><<<pgrid, 256, 0, stream>>>(
        x, pha, lna, lnb, WQ2, WK2, WV2, kt, vt, qt, meta, h1);
    tables_kernel<<<tgrid, 256, 0, stream>>>(kt, vt, meta, tab);
    rows_kernel<<<rgrid, 256, 0, stream>>>(kt, vt, qt, meta, tab, W02, phb);
    // layer 3: h2 = h1 + LN(combine(phb))
    prep_kernel<false><<<pgrid, 256, 0, stream>>>(
        h1, phb, lna, lnb, WQ3, WK3, WV3, kt, vt, qt, meta, h2);
    tables_kernel<<<tgrid, 256, 0, stream>>>(kt, vt, meta, tab);
    rows_kernel<<<rgrid, 256, 0, stream>>>(kt, vt, qt, meta, tab, W03, pha);
    // tail
    logits_kernel<<<dim3(NC, NB), 256, 0, stream>>>(
        h2, pha, lna, lnb, fcw, fcb, lgt);
    lsm_kernel<<<NB, 64, 0, stream>>>(lgt, out);
}

// Round 21
// 158.764 us; speedup vs baseline: 1.6512x; 1.1562x over previous
//
#include <hip/hip_runtime.h>
#include <math.h>

#define G      1708
#define GP     1728         // padded per-(b,h) row stride (div by 4)
#define C4     427          // float4 chunks per row (427*4 = 1708 exactly)
#define NH     5
#define NB     16
#define NC     34
#define NND    256          // interpolation nodes per (b,h)  (r18: 512)
#define NPB    16           // nodes per block (4 waves x 4 nodes)
#define LN_EPS 1e-6f
#define LOG2E  1.4426950408889634f
#define LN2    0.6931471805599453f

// ---------------------------------------------------------------------------
// Rank-1 attention via function tabulation (r16/r18-proven correct, absmax
// unchanged): S1_i = f(q_i), S2_i = g(q_i) with f(t)=sum_j exp(t k_j),
// g(t)=sum_j v_j exp(t k_j).  Tabulate {log2 f, dlog2f, g/f, d(g/f)} at NND
// uniform nodes; rows do cubic Hermite + exact diagonal correction.
// r19 change: NND 512 -> 256.  Interp error scales h^4 (x16 from a base
// invisible under the 0.03125 fp32-noise floor); tables work halves.
// ---------------------------------------------------------------------------

// prep: grid (NH,NB).  Recombine prev heads + LN (layers 2/3) -> h (regs),
// write k2 = h*WK*log2e, v = h*WV, q = h*WQ to global; reduce q/k2 min/max.
template <bool FIRST>
__global__ __launch_bounds__(256) void prep_kernel(
    const float* __restrict__ hprev, const float* __restrict__ php,
    const float* __restrict__ lna, const float* __restrict__ lnb,
    const float* __restrict__ WQ, const float* __restrict__ WK,
    const float* __restrict__ WV,
    float* __restrict__ kt, float* __restrict__ vt, float* __restrict__ qt,
    float* __restrict__ meta, float* __restrict__ hcur)
{
    __shared__ float red[16];
    const int h = blockIdx.x, b = blockIdx.y, tid = threadIdx.x;
    const size_t pbh = (size_t)b * NH + h;
    const float4* hp4 = reinterpret_cast<const float4*>(hprev + (size_t)b * G);

    // ---- phase A: combine heads (registers) + LN stats ----
    float4 acc0, acc1;
    float mean = 0.f, inv = 0.f;
    if constexpr (!FIRST) {
        const float4* p0 = reinterpret_cast<const float4*>(php + ((size_t)b * NH + 0) * GP);
        const float4* p1 = reinterpret_cast<const float4*>(php + ((size_t)b * NH + 1) * GP);
        const float4* p2 = reinterpret_cast<const float4*>(php + ((size_t)b * NH + 2) * GP);
        const float4* p3 = reinterpret_cast<const float4*>(php + ((size_t)b * NH + 3) * GP);
        const float4* p4 = reinterpret_cast<const float4*>(php + ((size_t)b * NH + 4) * GP);
        float s = 0.f, ss = 0.f;
        {   // it = 0: c = tid < 256 <= C4
            const int c = tid;
            float4 a = p0[c], t;
            t = p1[c]; a.x += t.x; a.y += t.y; a.z += t.z; a.w += t.w;
            t = p2[c]; a.x += t.x; a.y += t.y; a.z += t.z; a.w += t.w;
            t = p3[c]; a.x += t.x; a.y += t.y; a.z += t.z; a.w += t.w;
            t = p4[c]; a.x += t.x; a.y += t.y; a.z += t.z; a.w += t.w;
            acc0 = a;
            s  += (a.x + a.y) + (a.z + a.w);
            ss += (a.x * a.x + a.y * a.y) + (a.z * a.z + a.w * a.w);
        }
        {   // it = 1
            const int c = tid + 256;
            if (c < C4) {
                float4 a = p0[c], t;
                t = p1[c]; a.x += t.x; a.y += t.y; a.z += t.z; a.w += t.w;
                t = p2[c]; a.x += t.x; a.y += t.y; a.z += t.z; a.w += t.w;
                t = p3[c]; a.x += t.x; a.y += t.y; a.z += t.z; a.w += t.w;
                t = p4[c]; a.x += t.x; a.y += t.y; a.z += t.z; a.w += t.w;
                acc1 = a;
                s  += (a.x + a.y) + (a.z + a.w);
                ss += (a.x * a.x + a.y * a.y) + (a.z * a.z + a.w * a.w);
            }
        }
        for (int o = 1; o < 64; o <<= 1) {
            s  += __shfl_xor(s, o);
            ss += __shfl_xor(ss, o);
        }
        if ((tid & 63) == 0) { red[tid >> 6] = s; red[4 + (tid >> 6)] = ss; }
        __syncthreads();
        float S  = (red[0] + red[1]) + (red[2] + red[3]);
        float SS = (red[4] + red[5]) + (red[6] + red[7]);
        mean = S / (float)G;
        float var = fmaxf((SS - S * mean) / (float)(G - 1), 0.f);
        inv = 1.f / (sqrtf(var) + LN_EPS);
        __syncthreads();   // red reads done before minmax reuse
    }

    // ---- phase B: h values, k2/v/q rows to global, q & k2 min/max ----
    const float4* ga4 = reinterpret_cast<const float4*>(lna);
    const float4* gb4 = reinterpret_cast<const float4*>(lnb);
    const float4* wk4 = reinterpret_cast<const float4*>(WK + (size_t)h * G);
    const float4* wv4 = reinterpret_cast<const float4*>(WV + (size_t)h * G);
    const float4* wq4 = reinterpret_cast<const float4*>(WQ + (size_t)h * G);
    float4* kt4 = reinterpret_cast<float4*>(kt + pbh * GP);
    float4* vt4 = reinterpret_cast<float4*>(vt + pbh * GP);
    float4* qt4 = reinterpret_cast<float4*>(qt + pbh * GP);
    float4* hc4 = (!FIRST && hcur != nullptr && h == 0)
                      ? reinterpret_cast<float4*>(hcur + (size_t)b * G) : nullptr;

    float kmx = -INFINITY, kmn = INFINITY;
    float qmx = -INFINITY, qmn = INFINITY;
#pragma unroll
    for (int it = 0; it < 2; ++it) {
        const int c = tid + it * 256;
        if (it == 0 || c < C4) {
            float4 hv;
            if constexpr (FIRST) {
                hv = hp4[c];
            } else {
                float4 a = (it == 0) ? acc0 : acc1;
                float4 hp = hp4[c], ga = ga4[c], gb = gb4[c];
                hv.x = hp.x + ga.x * (a.x - mean) * inv + gb.x;
                hv.y = hp.y + ga.y * (a.y - mean) * inv + gb.y;
                hv.z = hp.z + ga.z * (a.z - mean) * inv + gb.z;
                hv.w = hp.w + ga.w * (a.w - mean) * inv + gb.w;
            }
            if (hc4) hc4[c] = hv;
            float4 wk = wk4[c], wv = wv4[c], wq = wq4[c], kl, vv, qv;
            kl.x = hv.x * wk.x * LOG2E; kl.y = hv.y * wk.y * LOG2E;
            kl.z = hv.z * wk.z * LOG2E; kl.w = hv.w * wk.w * LOG2E;
            vv.x = hv.x * wv.x; vv.y = hv.y * wv.y;
            vv.z = hv.z * wv.z; vv.w = hv.w * wv.w;
            qv.x = hv.x * wq.x; qv.y = hv.y * wq.y;
            qv.z = hv.z * wq.z; qv.w = hv.w * wq.w;
            kt4[c] = kl;
            vt4[c] = vv;
            qt4[c] = qv;
            kmx = fmaxf(kmx, fmaxf(fmaxf(kl.x, kl.y), fmaxf(kl.z, kl.w)));
            kmn = fminf(kmn, fminf(fminf(kl.x, kl.y), fminf(kl.z, kl.w)));
            qmx = fmaxf(qmx, fmaxf(fmaxf(qv.x, qv.y), fmaxf(qv.z, qv.w)));
            qmn = fminf(qmn, fminf(fminf(qv.x, qv.y), fminf(qv.z, qv.w)));
        }
    }
    for (int o = 1; o < 64; o <<= 1) {
        kmx = fmaxf(kmx, __shfl_xor(kmx, o));
        kmn = fminf(kmn, __shfl_xor(kmn, o));
        qmx = fmaxf(qmx, __shfl_xor(qmx, o));
        qmn = fminf(qmn, __shfl_xor(qmn, o));
    }
    if ((tid & 63) == 0) {
        red[tid >> 6]      = qmn; red[4 + (tid >> 6)]  = qmx;
        red[8 + (tid >> 6)] = kmn; red[12 + (tid >> 6)] = kmx;
    }
    __syncthreads();
    if (tid == 0) {
        meta[pbh * 4 + 0] = fminf(fminf(red[0], red[1]), fminf(red[2], red[3]));
        meta[pbh * 4 + 1] = fmaxf(fmaxf(red[4], red[5]), fmaxf(red[6], red[7]));
        meta[pbh * 4 + 2] = fminf(fminf(red[8], red[9]), fminf(red[10], red[11]));
        meta[pbh * 4 + 3] = fmaxf(fmaxf(red[12], red[13]), fmaxf(red[14], red[15]));
    }
}

// tables: grid (NND/NPB, NH, NB) = (16,5,16) = 1280 blocks.  k/v staged in
// LDS once per block; each of 4 waves owns 4 nodes in registers; j-loop
// reads float4 pairs from LDS feeding 16 exps per chunk per wave.
__global__ __launch_bounds__(256, 8) void tables_kernel(
    const float* __restrict__ kt, const float* __restrict__ vt,
    const float* __restrict__ meta, float4* __restrict__ tab)
{
    __shared__ __align__(16) float krow[G];
    __shared__ __align__(16) float vrow[G];

    const int ng = blockIdx.x, h = blockIdx.y, b = blockIdx.z;
    const size_t pbh = (size_t)b * NH + h;
    const int tid = threadIdx.x;
    const int w = tid >> 6, lane = tid & 63;

    // stage k/v rows into LDS
    const float4* ktg = reinterpret_cast<const float4*>(kt + pbh * GP);
    const float4* vtg = reinterpret_cast<const float4*>(vt + pbh * GP);
    float4* kr4 = reinterpret_cast<float4*>(krow);
    float4* vr4 = reinterpret_cast<float4*>(vrow);
    for (int c = tid; c < C4; c += 256) { kr4[c] = ktg[c]; vr4[c] = vtg[c]; }

    const float qmn = meta[pbh * 4 + 0], qmx = meta[pbh * 4 + 1];
    const float kmn = meta[pbh * 4 + 2], kmx = meta[pbh * 4 + 3];
    const float rng = fmaxf(qmx - qmn, 1e-6f);
    const int nb = ng * NPB + w * 4;

    float t[4], m2[4], F[4], G1[4], Gv[4], G2[4];
#pragma unroll
    for (int r = 0; r < 4; ++r) {
        t[r]  = qmn + rng * ((float)(nb + r) / (float)(NND - 1));
        m2[r] = fmaxf(t[r] * kmx, t[r] * kmn);
        F[r] = 0.f; G1[r] = 0.f; Gv[r] = 0.f; G2[r] = 0.f;
    }
    __syncthreads();

    for (int c = lane; c < C4; c += 64) {
        const float4 kk = kr4[c];
        const float4 vv = vr4[c];
#pragma unroll
        for (int r = 0; r < 4; ++r) {
            const float tt = t[r], mm = m2[r];
            const float e0 = __builtin_amdgcn_exp2f(fmaf(tt, kk.x, -mm));
            const float e1 = __builtin_amdgcn_exp2f(fmaf(tt, kk.y, -mm));
            const float e2 = __builtin_amdgcn_exp2f(fmaf(tt, kk.z, -mm));
            const float e3 = __builtin_amdgcn_exp2f(fmaf(tt, kk.w, -mm));
            F[r] += (e0 + e1) + (e2 + e3);
            G1[r] = fmaf(kk.x, e0, G1[r]);
            G1[r] = fmaf(kk.y, e1, G1[r]);
            G1[r] = fmaf(kk.z, e2, G1[r]);
            G1[r] = fmaf(kk.w, e3, G1[r]);
            const float ve0 = vv.x * e0, ve1 = vv.y * e1;
            const float ve2 = vv.z * e2, ve3 = vv.w * e3;
            Gv[r] += (ve0 + ve1) + (ve2 + ve3);
            G2[r] = fmaf(kk.x, ve0, G2[r]);
            G2[r] = fmaf(kk.y, ve1, G2[r]);
            G2[r] = fmaf(kk.z, ve2, G2[r]);
            G2[r] = fmaf(kk.w, ve3, G2[r]);
        }
    }

#pragma unroll
    for (int r = 0; r < 4; ++r) {
        for (int o = 1; o < 64; o <<= 1) {
            F[r]  += __shfl_xor(F[r], o);
            G1[r] += __shfl_xor(G1[r], o);
            Gv[r] += __shfl_xor(Gv[r], o);
            G2[r] += __shfl_xor(G2[r], o);
        }
    }
    if (lane == 0) {
#pragma unroll
        for (int r = 0; r < 4; ++r) {
            float4 T;
            T.x = m2[r] + __builtin_amdgcn_logf(F[r]);          // log2 f
            T.y = G1[r] / F[r];                                 // dlog2f/dt
            T.z = Gv[r] / F[r];                                 // G = g/f
            T.w = LN2 * (G2[r] * F[r] - Gv[r] * G1[r]) / (F[r] * F[r]); // dG/dt
            tab[pbh * NND + nb + r] = T;
        }
    }
}

// rows: grid (7, NH, NB).  One row per thread: cubic Hermite eval of
// log2 f and G at t = q_i, then exact diagonal correction.
__global__ __launch_bounds__(256) void rows_kernel(
    const float* __restrict__ kt, const float* __restrict__ vt,
    const float* __restrict__ qt, const float* __restrict__ meta,
    const float4* __restrict__ tab, const float* __restrict__ W0,
    float* __restrict__ ph)
{
    const int h = blockIdx.y, b = blockIdx.z;
    const int i = blockIdx.x * 256 + threadIdx.x;
    if (i >= G) return;
    const size_t pbh = (size_t)b * NH + h;

    const float qmn = meta[pbh * 4 + 0], qmx = meta[pbh * 4 + 1];
    const float rng = fmaxf(qmx - qmn, 1e-6f);
    const float hstep = rng / (float)(NND - 1);
    const float t = qt[pbh * GP + i];

    float u = (t - qmn) / hstep;
    int n = (int)floorf(u);
    n = n < 0 ? 0 : (n > NND - 2 ? NND - 2 : n);
    float s = u - (float)n;
    s = s < 0.f ? 0.f : (s > 1.f ? 1.f : s);

    const float4 T0 = tab[pbh * NND + n];
    const float4 T1 = tab[pbh * NND + n + 1];
    const float s2 = s * s, s3 = s2 * s;
    const float h00 = 2.f * s3 - 3.f * s2 + 1.f;
    const float h10 = s3 - 2.f * s2 + s;
    const float h01 = 3.f * s2 - 2.f * s3;
    const float h11 = s3 - s2;

    const float log2f = T0.x * h00 + T1.x * h01 + hstep * (T0.y * h10 + T1.y * h11);
    const float Gval  = T0.z * h00 + T1.z * h01 + hstep * (T0.w * h10 + T1.w * h11);

    const float k2i = kt[pbh * GP + i];
    const float vi  = vt[pbh * GP + i];
    const float eof = __builtin_amdgcn_exp2f(fmaf(t, k2i, -log2f));  // arg <= 0
    ph[pbh * GP + i] = W0[h] * (Gval - vi * eof);
}

// ---------------------------------------------------------------------------
// One logit per block: recombine layer-3 heads + LN on the fly, dot with
// fc row c.  grid (NC, NB) = 544 blocks.  (proven, unchanged)
// ---------------------------------------------------------------------------
__global__ __launch_bounds__(256) void logits_kernel(
    const float* __restrict__ hprev, const float* __restrict__ php,
    const float* __restrict__ lna, const float* __restrict__ lnb,
    const float* __restrict__ fcw, const float* __restrict__ fcb,
    float* __restrict__ lgt)
{
    __shared__ __align__(16) float arow[G];
    __shared__ float red[8];
    const int c = blockIdx.x, b = blockIdx.y, tid = threadIdx.x;

    const float4* p0 = reinterpret_cast<const float4*>(php + ((size_t)b * NH + 0) * GP);
    const float4* p1 = reinterpret_cast<const float4*>(php + ((size_t)b * NH + 1) * GP);
    const float4* p2 = reinterpret_cast<const float4*>(php + ((size_t)b * NH + 2) * GP);
    const float4* p3 = reinterpret_cast<const float4*>(php + ((size_t)b * NH + 3) * GP);
    const float4* p4 = reinterpret_cast<const float4*>(php + ((size_t)b * NH + 4) * GP);
    float4* ar4 = reinterpret_cast<float4*>(arow);

    float s = 0.f, ss = 0.f;
    for (int k = tid; k < C4; k += 256) {
        float4 a = p0[k], t;
        t = p1[k]; a.x += t.x; a.y += t.y; a.z += t.z; a.w += t.w;
        t = p2[k]; a.x += t.x; a.y += t.y; a.z += t.z; a.w += t.w;
        t = p3[k]; a.x += t.x; a.y += t.y; a.z += t.z; a.w += t.w;
        t = p4[k]; a.x += t.x; a.y += t.y; a.z += t.z; a.w += t.w;
        ar4[k] = a;
        s  += (a.x + a.y) + (a.z + a.w);
        ss += (a.x * a.x + a.y * a.y) + (a.z * a.z + a.w * a.w);
    }
    for (int o = 1; o < 64; o <<= 1) {
        s  += __shfl_xor(s, o);
        ss += __shfl_xor(ss, o);
    }
    if ((tid & 63) == 0) { red[tid >> 6] = s; red[4 + (tid >> 6)] = ss; }
    __syncthreads();
    float S  = (red[0] + red[1]) + (red[2] + red[3]);
    float SS = (red[4] + red[5]) + (red[6] + red[7]);
    const float mean = S / (float)G;
    const float var  = fmaxf((SS - S * mean) / (float)(G - 1), 0.f);
    const float inv  = 1.f / (sqrtf(var) + LN_EPS);

    const float4* hp4 = reinterpret_cast<const float4*>(hprev + (size_t)b * G);
    const float4* ga4 = reinterpret_cast<const float4*>(lna);
    const float4* gb4 = reinterpret_cast<const float4*>(lnb);
    const float4* w4  = reinterpret_cast<const float4*>(fcw + (size_t)c * G);
    float acc = 0.f;
    for (int k = tid; k < C4; k += 256) {
        float4 a = ar4[k], hp = hp4[k], ga = ga4[k], gb = gb4[k], w = w4[k];
        float hx = hp.x + ga.x * (a.x - mean) * inv + gb.x;
        float hy = hp.y + ga.y * (a.y - mean) * inv + gb.y;
        float hz = hp.z + ga.z * (a.z - mean) * inv + gb.z;
        float hw = hp.w + ga.w * (a.w - mean) * inv + gb.w;
        acc += (hx * w.x + hy * w.y) + (hz * w.z + hw * w.w);
    }
    for (int o = 1; o < 64; o <<= 1) acc += __shfl_xor(acc, o);
    __syncthreads();
    if ((tid & 63) == 0) red[tid >> 6] = acc;
    __syncthreads();
    if (tid == 0)
        lgt[(size_t)b * NC + c] =
            (red[0] + red[1]) + (red[2] + red[3]) + fcb[c];
}

// out = log_softmax(logits) — one wave per batch row  (proven)
__global__ __launch_bounds__(64) void lsm_kernel(
    const float* __restrict__ lgt, float* __restrict__ out)
{
    const int b = blockIdx.x, tid = threadIdx.x;
    float l = (tid < NC) ? lgt[(size_t)b * NC + tid] : -INFINITY;
    float mm = l;
    for (int o = 32; o; o >>= 1) mm = fmaxf(mm, __shfl_xor(mm, o));
    float e = (tid < NC) ? expf(l - mm) : 0.f;
    float se = e;
    for (int o = 32; o; o >>= 1) se += __shfl_xor(se, o);
    if (tid < NC) out[(size_t)b * NC + tid] = l - mm - logf(se);
}

// ---------------------------------------------------------------------------
extern "C" void kernel_launch(void* const* d_in, const int* in_sizes, int n_in,
                              void* d_out, int out_size, void* d_ws, size_t ws_size,
                              hipStream_t stream)
{
    const float* x    = (const float*)d_in[0];
    const float* WQ1  = (const float*)d_in[1];
    const float* WK1  = (const float*)d_in[2];
    const float* WV1  = (const float*)d_in[3];
    const float* W01  = (const float*)d_in[4];
    const float* WQ2  = (const float*)d_in[5];
    const float* WK2  = (const float*)d_in[6];
    const float* WV2  = (const float*)d_in[7];
    const float* W02  = (const float*)d_in[8];
    const float* WQ3  = (const float*)d_in[9];
    const float* WK3  = (const float*)d_in[10];
    const float* WV3  = (const float*)d_in[11];
    const float* W03  = (const float*)d_in[12];
    const float* lna  = (const float*)d_in[13];
    const float* lnb  = (const float*)d_in[14];
    const float* fcw  = (const float*)d_in[15];
    const float* fcb  = (const float*)d_in[16];
    float* out = (float*)d_out;

    const size_t PHS = (size_t)NB * NH * GP;     // 138240 floats (div 4)
    float* kt   = (float*)d_ws;                  // [NB*NH, GP] k*log2e
    float* vt   = kt + PHS;                      // [NB*NH, GP] v
    float* qt   = vt + PHS;                      // [NB*NH, GP] q
    float* pha  = qt + PHS;                      // per-head rows (L1/L3)
    float* phb  = pha + PHS;                     // per-head rows (L2)
    float* h1   = phb + PHS;                     // [NB,G]
    float* h2   = h1 + (size_t)NB * G;           // [NB,G]
    float* tabf = h2 + (size_t)NB * G;           // [NB*NH, NND] float4
    float4* tab = reinterpret_cast<float4*>(tabf);
    float* meta = tabf + (size_t)NB * NH * NND * 4;  // [NB*NH, 4]
    float* lgt  = meta + (size_t)NB * NH * 4;    // [NB,NC]

    const dim3 pgrid(NH, NB);                    // 80 blocks
    const dim3 tgrid(NND / NPB, NH, NB);         // (16,5,16) = 1280 blocks
    const dim3 rgrid(7, NH, NB);                 // 560 blocks (7*256 >= G)

    // layer 1
    prep_kernel<true><<<pgrid, 256, 0, stream>>>(
        x, nullptr, lna, lnb, WQ1, WK1, WV1, kt, vt, qt, meta, nullptr);
    tables_kernel<<<tgrid, 256, 0, stream>>>(kt, vt, meta, tab);
    rows_kernel<<<rgrid, 256, 0, stream>>>(kt, vt, qt, meta, tab, W01, pha);
    // layer 2: h1 = x + LN(combine(pha))
    prep_kernel<false><<<pgrid, 256, 0, stream>>>(
        x, pha, lna, lnb, WQ2, WK2, WV2, kt, vt, qt, meta, h1);
    tables_kernel<<<tgrid, 256, 0, stream>>>(kt, vt, meta, tab);
    rows_kernel<<<rgrid, 256, 0, stream>>>(kt, vt, qt, meta, tab, W02, phb);
    // layer 3: h2 = h1 + LN(combine(phb))
    prep_kernel<false><<<pgrid, 256, 0, stream>>>(
        h1, phb, lna, lnb, WQ3, WK3, WV3, kt, vt, qt, meta, h2);
    tables_kernel<<<tgrid, 256, 0, stream>>>(kt, vt, meta, tab);
    rows_kernel<<<rgrid, 256, 0, stream>>>(kt, vt, qt, meta, tab, W03, pha);
    // tail
    logits_kernel<<<dim3(NC, NB), 256, 0, stream>>>(
        h2, pha, lna, lnb, fcw, fcb, lgt);
    lsm_kernel<<<NB, 64, 0, stream>>>(lgt, out);
}